// Round 4
// baseline (394.633 us; speedup 1.0000x reference)
//
#include <hip/hip_runtime.h>
#include <hip/hip_fp16.h>

#define BB 8
#define LL 1024
#define DIN 256
#define DM 512
#define HH 8
#define DH 64

typedef __attribute__((ext_vector_type(8))) short bf16x8;
typedef __attribute__((ext_vector_type(4))) float f32x4;

__device__ __forceinline__ unsigned short f2bf(float f) {
  union { float f; unsigned u; } c; c.f = f;
  unsigned u = c.u;
  return (unsigned short)((u + 0x7fffu + ((u >> 16) & 1u)) >> 16);
}

#if defined(__has_builtin)
#if __has_builtin(__builtin_amdgcn_cvt_pk_bf16_f32)
#define HAS_PK_BF16 1
#endif
#endif

#ifdef HAS_PK_BF16
typedef __bf16 bf2 __attribute__((ext_vector_type(2)));
__device__ __forceinline__ unsigned pk2(float lo, float hi) {
  union { bf2 v; unsigned u; } c;
  c.v = __builtin_amdgcn_cvt_pk_bf16_f32(lo, hi);
  return c.u;
}
#else
__device__ __forceinline__ unsigned pk2(float lo, float hi) {
  return ((unsigned)f2bf(hi) << 16) | f2bf(lo);
}
#endif

// pack (adj, dis) as two RNE fp16 in one dword
__device__ __forceinline__ unsigned pkh(float a, float d) {
  return (unsigned)__half_as_ushort(__float2half_rn(a)) |
         ((unsigned)__half_as_ushort(__float2half_rn(d)) << 16);
}

// ---------------- K0: merged precast ----------------
// X,W -> bf16; mask -> additive f32; (adj,dis) -> packed fp16 pair stream.
__global__ __launch_bounds__(256) void prep(
    const float* __restrict__ qin, const float* __restrict__ kin,
    const float* __restrict__ vin,
    const float* __restrict__ wq, const float* __restrict__ wk,
    const float* __restrict__ wv, const float* __restrict__ wo,
    const int* __restrict__ msk,
    const float* __restrict__ adj, const float* __restrict__ dis,
    unsigned short* __restrict__ xq, unsigned short* __restrict__ xk,
    unsigned short* __restrict__ xv,
    unsigned short* __restrict__ wqb, unsigned short* __restrict__ wkb,
    unsigned short* __restrict__ wvb, unsigned short* __restrict__ wob,
    float* __restrict__ mad, unsigned* __restrict__ bp)
{
  int t = blockIdx.x * 256 + threadIdx.x;  // quad index
  const int XS = 524288, WS = 32768;
  if (t < 3 * XS) {
    int seg = t >> 19, off = t & (XS - 1);
    const float* s = (seg == 0) ? qin : (seg == 1) ? kin : vin;
    unsigned short* d = (seg == 0) ? xq : (seg == 1) ? xk : xv;
    float4 f = ((const float4*)s)[off];
    uint2 o = { pk2(f.x, f.y), pk2(f.z, f.w) };
    ((uint2*)d)[off] = o;
    return;
  }
  t -= 3 * XS;
  if (t < 3 * WS) {
    int seg = t >> 15, off = t & (WS - 1);
    const float* s = (seg == 0) ? wq : (seg == 1) ? wk : wv;
    unsigned short* d = (seg == 0) ? wqb : (seg == 1) ? wkb : wvb;
    float4 f = ((const float4*)s)[off];
    uint2 o = { pk2(f.x, f.y), pk2(f.z, f.w) };
    ((uint2*)d)[off] = o;
    return;
  }
  t -= 3 * WS;
  if (t < 65536) {
    float4 f = ((const float4*)wo)[t];
    uint2 o = { pk2(f.x, f.y), pk2(f.z, f.w) };
    ((uint2*)wob)[t] = o;
    return;
  }
  t -= 65536;
  if (t < 2048) {  // mask -> additive bias (log2 domain)
    int4 m = ((const int4*)msk)[t];
    float4 f = { m.x ? 0.0f : -30000.0f, m.y ? 0.0f : -30000.0f,
                 m.z ? 0.0f : -30000.0f, m.w ? 0.0f : -30000.0f };
    ((float4*)mad)[t] = f;
    return;
  }
  t -= 2048;  // bias pack: 2,097,152 quads
  float4 a4 = ((const float4*)adj)[t];
  float4 d4 = ((const float4*)dis)[t];
  uint4 o = { pkh(a4.x, d4.x), pkh(a4.y, d4.y), pkh(a4.z, d4.z), pkh(a4.w, d4.w) };
  ((uint4*)bp)[t] = o;
}

// ---------------- K1: QKV projection (bf16 in, bf16 out) ----------------
__global__ __launch_bounds__(256) void qkv_proj(
    const unsigned short* __restrict__ xq, const unsigned short* __restrict__ xk,
    const unsigned short* __restrict__ xv,
    const unsigned short* __restrict__ wqb, const unsigned short* __restrict__ wkb,
    const unsigned short* __restrict__ wvb,
    unsigned short* __restrict__ qb, unsigned short* __restrict__ kb,
    unsigned short* __restrict__ vt)
{
  const int t = blockIdx.z;
  const unsigned short* __restrict__ X = (t == 0) ? xq : (t == 1) ? xk : xv;
  const unsigned short* __restrict__ W = (t == 0) ? wqb : (t == 1) ? wkb : wvb;
  const int m0 = blockIdx.y * 128;
  const int h  = blockIdx.x;
  __shared__ unsigned short As[128 * 40];
  __shared__ unsigned short Bs[64 * 40];
  const int tid = threadIdx.x;
  const int wid = tid >> 6;
  const int lane = tid & 63;
  const int lo = lane & 15;
  const int quad = lane >> 4;

  f32x4 acc[2][4];
#pragma unroll
  for (int mi = 0; mi < 2; ++mi)
#pragma unroll
    for (int ni = 0; ni < 4; ++ni) acc[mi][ni] = (f32x4)0.0f;

  for (int kk = 0; kk < DIN; kk += 32) {
#pragma unroll
    for (int i = 0; i < 2; ++i) {
      int id = i * 256 + tid;
      int row = id >> 2, ch = id & 3;
      *(uint4*)&As[row * 40 + ch * 8] =
          *(const uint4*)&X[(size_t)(m0 + row) * DIN + kk + ch * 8];
    }
    {
      int row = tid >> 2, ch = tid & 3;
      *(uint4*)&Bs[row * 40 + ch * 8] =
          *(const uint4*)&W[(size_t)(h * 64 + row) * DIN + kk + ch * 8];
    }
    __syncthreads();
    bf16x8 a[2], bfr[4];
#pragma unroll
    for (int mi = 0; mi < 2; ++mi)
      a[mi] = *(const bf16x8*)&As[(wid * 32 + mi * 16 + lo) * 40 + quad * 8];
#pragma unroll
    for (int ni = 0; ni < 4; ++ni)
      bfr[ni] = *(const bf16x8*)&Bs[(ni * 16 + lo) * 40 + quad * 8];
#pragma unroll
    for (int mi = 0; mi < 2; ++mi)
#pragma unroll
      for (int ni = 0; ni < 4; ++ni)
        acc[mi][ni] = __builtin_amdgcn_mfma_f32_16x16x32_bf16(
            a[mi], bfr[ni], acc[mi][ni], 0, 0, 0);
    __syncthreads();
  }

  const int b = m0 >> 10;
  const int lbase0 = (m0 & 1023) + wid * 32;
  if (t < 2) {
    unsigned short* dstp = (t == 0) ? qb : kb;
#pragma unroll
    for (int mi = 0; mi < 2; ++mi)
#pragma unroll
      for (int ni = 0; ni < 4; ++ni) {
        int d = ni * 16 + lo;
#pragma unroll
        for (int r = 0; r < 4; ++r) {
          int lb = lbase0 + mi * 16 + quad * 4 + r;
          dstp[((size_t)(b * HH + h) * LL + lb) * DH + d] = f2bf(acc[mi][ni][r]);
        }
      }
  } else {
#pragma unroll
    for (int mi = 0; mi < 2; ++mi)
#pragma unroll
      for (int ni = 0; ni < 4; ++ni) {
        int d = ni * 16 + lo;
        int lb = lbase0 + mi * 16 + quad * 4;
        uint2 o = { pk2(acc[mi][ni][0], acc[mi][ni][1]),
                    pk2(acc[mi][ni][2], acc[mi][ni][3]) };
        *(uint2*)&vt[((size_t)(b * HH + h) * DH + d) * LL + lb] = o;
      }
  }
}

// ---------------- K2: fused biased attention, deep-pipelined ----------
// grid 1024: idx = qt*32 + hg*8 + b (XCD swizzle). 4 waves/block:
// (h = hg*2 + wid&1, K-half = wid>>1). Register-rotated prefetch:
// bias distance 4 (4 slots), mask distance 2, kA distance 1.
__global__ __launch_bounds__(256, 3) void attn(
    const unsigned short* __restrict__ qb, const unsigned short* __restrict__ kb,
    const unsigned short* __restrict__ vt,
    const float* __restrict__ mad, const unsigned* __restrict__ bp,
    const float* __restrict__ la_, const float* __restrict__ ld_,
    unsigned short* __restrict__ ao)
{
  const int bi = blockIdx.x;
  const int b  = bi & 7;
  const int hg = (bi >> 3) & 3;
  const int q0 = (bi >> 5) * 32;
  const int tid = threadIdx.x;
  const int wid = tid >> 6;
  const int lane = tid & 63;
  const int lo = lane & 15;
  const int quad = lane >> 4;
  const int h  = hg * 2 + (wid & 1);
  const int kh = wid >> 1;
  const int bh = b * HH + h;

  __shared__ __align__(16) unsigned short pbuf[4][32 * 40];
  __shared__ __align__(16) float mbuf[2][34 * 64];

  const float LOG2E = 1.44269504f;
  const float la2 = la_[h] * LOG2E, ld2 = ld_[h] * LOG2E;
  const float sc2 = 0.125f * LOG2E;

  const unsigned short* qp = qb + ((size_t)bh * LL + q0) * DH;
  bf16x8 qB[2][2];
#pragma unroll
  for (int nj = 0; nj < 2; ++nj)
#pragma unroll
    for (int ki = 0; ki < 2; ++ki)
      qB[nj][ki] = *(const bf16x8*)&qp[(nj * 16 + lo) * DH + ki * 32 + quad * 8];

  const unsigned short* kp = kb + (size_t)bh * LL * DH;
  const unsigned short* vp = vt + (size_t)bh * DH * LL;
  const unsigned* bpp = bp + ((size_t)b * LL + q0) * LL;
  const float* mp = mad + b * LL;

  f32x4 o[4][2];
  float rs[2] = {0.0f, 0.0f};
#pragma unroll
  for (int md = 0; md < 4; ++md)
#pragma unroll
    for (int nj = 0; nj < 2; ++nj) o[md][nj] = (f32x4)0.0f;

  const int kbeg = kh * (LL / 2);

  // rotation slots
  uint4  bs[4][4];     // [slot][mi*2+nj] packed (f16 adj, f16 dis) x4 k
  f32x4  ms[2][2];     // [slot][mi] mask additive
  bf16x8 kA2[2][2][2]; // [slot][mi][ki]

#pragma unroll
  for (int p = 0; p < 4; ++p)
#pragma unroll
    for (int mi = 0; mi < 2; ++mi)
#pragma unroll
      for (int nj = 0; nj < 2; ++nj)
        bs[p][mi * 2 + nj] = *(const uint4*)&bpp[(size_t)(nj * 16 + lo) * LL +
                                                 kbeg + p * 32 + mi * 16 + quad * 4];
#pragma unroll
  for (int p = 0; p < 2; ++p)
#pragma unroll
    for (int mi = 0; mi < 2; ++mi)
      ms[p][mi] = *(const f32x4*)&mp[kbeg + p * 32 + mi * 16 + quad * 4];
#pragma unroll
  for (int mi = 0; mi < 2; ++mi)
#pragma unroll
    for (int ki = 0; ki < 2; ++ki)
      kA2[0][mi][ki] = *(const bf16x8*)&kp[(kbeg + mi * 16 + lo) * DH + ki * 32 + quad * 8];

#pragma unroll 4
  for (int j = 0; j < 16; ++j) {
    const int kt  = kbeg + j * 32;
    const int kn1 = kbeg + ((j + 1) & 15) * 32;
    const int kn2 = kbeg + ((j + 2) & 15) * 32;
    const int kn4 = kbeg + ((j + 4) & 15) * 32;

    // V^T for current tile (L2-resident)
    bf16x8 vA[4];
#pragma unroll
    for (int md = 0; md < 4; ++md)
      vA[md] = *(const bf16x8*)&vp[(md * 16 + lo) * LL + kt + quad * 8];

    // S^T = K Q^T (consumes kA slot j&1)
    f32x4 s[2][2];
#pragma unroll
    for (int mi = 0; mi < 2; ++mi)
#pragma unroll
      for (int nj = 0; nj < 2; ++nj) s[mi][nj] = (f32x4)0.0f;
#pragma unroll
    for (int ki = 0; ki < 2; ++ki)
#pragma unroll
      for (int mi = 0; mi < 2; ++mi)
#pragma unroll
        for (int nj = 0; nj < 2; ++nj)
          s[mi][nj] = __builtin_amdgcn_mfma_f32_16x16x32_bf16(
              kA2[j & 1][mi][ki], qB[nj][ki], s[mi][nj], 0, 0, 0);

    // kA for tile j+1 -> other slot
#pragma unroll
    for (int mi = 0; mi < 2; ++mi)
#pragma unroll
      for (int ki = 0; ki < 2; ++ki)
        kA2[(j + 1) & 1][mi][ki] =
            *(const bf16x8*)&kp[(kn1 + mi * 16 + lo) * DH + ki * 32 + quad * 8];

    // bias + mask + exp2 (fma_mix pattern), pack P^T, 4x ds_write_b64
#pragma unroll
    for (int mi = 0; mi < 2; ++mi)
#pragma unroll
      for (int nj = 0; nj < 2; ++nj) {
        uint4 u = bs[j & 3][mi * 2 + nj];
        float p[4];
#pragma unroll
        for (int r = 0; r < 4; ++r) {
          union { unsigned v; __half2 h; } c; c.v = u[r];
          float tt = fmaf(__high2float(c.h), ld2, ms[j & 1][mi][r]);
          tt = fmaf(__low2float(c.h), la2, tt);
          p[r] = __builtin_amdgcn_exp2f(fmaf(s[mi][nj][r], sc2, tt));
        }
        rs[nj] += (p[0] + p[1]) + (p[2] + p[3]);
        uint2 w = { pk2(p[0], p[1]), pk2(p[2], p[3]) };
        *(uint2*)&pbuf[wid][(nj * 16 + lo) * 40 + mi * 16 + quad * 4] = w;
      }

    // reload consumed slots: bias tile j+4, mask tile j+2
#pragma unroll
    for (int mi = 0; mi < 2; ++mi)
#pragma unroll
      for (int nj = 0; nj < 2; ++nj)
        bs[j & 3][mi * 2 + nj] = *(const uint4*)&bpp[(size_t)(nj * 16 + lo) * LL +
                                                     kn4 + mi * 16 + quad * 4];
#pragma unroll
    for (int mi = 0; mi < 2; ++mi)
      ms[j & 1][mi] = *(const f32x4*)&mp[kn2 + mi * 16 + quad * 4];

    asm volatile("s_waitcnt lgkmcnt(0)" ::: "memory");

    bf16x8 pB[2];
#pragma unroll
    for (int nj = 0; nj < 2; ++nj)
      pB[nj] = *(const bf16x8*)&pbuf[wid][(nj * 16 + lo) * 40 + quad * 8];

#pragma unroll
    for (int md = 0; md < 4; ++md)
#pragma unroll
      for (int nj = 0; nj < 2; ++nj)
        o[md][nj] = __builtin_amdgcn_mfma_f32_16x16x32_bf16(
            vA[md], pB[nj], o[md][nj], 0, 0, 0);
  }

  // merge the two K-halves
  const int hs = wid & 1;
  if (kh == 1) {
#pragma unroll
    for (int md = 0; md < 4; ++md)
#pragma unroll
      for (int nj = 0; nj < 2; ++nj)
#pragma unroll
        for (int r = 0; r < 4; ++r)
          mbuf[hs][((md * 2 + nj) * 4 + r) * 64 + lane] = o[md][nj][r];
    mbuf[hs][32 * 64 + lane] = rs[0];
    mbuf[hs][33 * 64 + lane] = rs[1];
  }
  __syncthreads();
  if (kh == 0) {
#pragma unroll
    for (int md = 0; md < 4; ++md)
#pragma unroll
      for (int nj = 0; nj < 2; ++nj)
#pragma unroll
        for (int r = 0; r < 4; ++r)
          o[md][nj][r] += mbuf[hs][((md * 2 + nj) * 4 + r) * 64 + lane];
    rs[0] += mbuf[hs][32 * 64 + lane];
    rs[1] += mbuf[hs][33 * 64 + lane];
    float inv[2];
#pragma unroll
    for (int nj = 0; nj < 2; ++nj) {
      rs[nj] += __shfl_xor(rs[nj], 16);
      rs[nj] += __shfl_xor(rs[nj], 32);
      inv[nj] = __builtin_amdgcn_rcpf(rs[nj]);
    }
#pragma unroll
    for (int md = 0; md < 4; ++md)
#pragma unroll
      for (int nj = 0; nj < 2; ++nj) {
        int l = q0 + nj * 16 + lo;
        uint2 st = { pk2(o[md][nj][0] * inv[nj], o[md][nj][1] * inv[nj]),
                     pk2(o[md][nj][2] * inv[nj], o[md][nj][3] * inv[nj]) };
        *(uint2*)&ao[((size_t)b * LL + l) * DM + h * DH + md * 16 + quad * 4] = st;
      }
  }
}

// ---------------- K3: output projection ----------------
__global__ __launch_bounds__(256) void oproj(
    const unsigned short* __restrict__ ao, const unsigned short* __restrict__ wob,
    float* __restrict__ out)
{
  const int m0 = blockIdx.y * 128;
  const int n0 = blockIdx.x * 64;
  __shared__ unsigned short As[128 * 40];
  __shared__ unsigned short Bs[64 * 40];
  const int tid = threadIdx.x;
  const int wid = tid >> 6;
  const int lane = tid & 63;
  const int lo = lane & 15;
  const int quad = lane >> 4;

  f32x4 acc[2][4];
#pragma unroll
  for (int mi = 0; mi < 2; ++mi)
#pragma unroll
    for (int ni = 0; ni < 4; ++ni) acc[mi][ni] = (f32x4)0.0f;

  for (int kk = 0; kk < DM; kk += 32) {
#pragma unroll
    for (int i = 0; i < 2; ++i) {
      int id = i * 256 + tid;
      int row = id >> 2, ch = id & 3;
      *(uint4*)&As[row * 40 + ch * 8] =
          *(const uint4*)&ao[(size_t)(m0 + row) * DM + kk + ch * 8];
    }
    {
      int row = tid >> 2, ch = tid & 3;
      *(uint4*)&Bs[row * 40 + ch * 8] =
          *(const uint4*)&wob[(size_t)(n0 + row) * DM + kk + ch * 8];
    }
    __syncthreads();
    bf16x8 a[2], bfr[4];
#pragma unroll
    for (int mi = 0; mi < 2; ++mi)
      a[mi] = *(const bf16x8*)&As[(wid * 32 + mi * 16 + lo) * 40 + quad * 8];
#pragma unroll
    for (int ni = 0; ni < 4; ++ni)
      bfr[ni] = *(const bf16x8*)&Bs[(ni * 16 + lo) * 40 + quad * 8];
#pragma unroll
    for (int mi = 0; mi < 2; ++mi)
#pragma unroll
      for (int ni = 0; ni < 4; ++ni)
        acc[mi][ni] = __builtin_amdgcn_mfma_f32_16x16x32_bf16(
            a[mi], bfr[ni], acc[mi][ni], 0, 0, 0);
    __syncthreads();
  }

#pragma unroll
  for (int mi = 0; mi < 2; ++mi)
#pragma unroll
    for (int ni = 0; ni < 4; ++ni)
#pragma unroll
      for (int r = 0; r < 4; ++r)
        out[(size_t)(m0 + wid * 32 + mi * 16 + quad * 4 + r) * DM +
            n0 + ni * 16 + lo] = acc[mi][ni][r];
}

extern "C" void kernel_launch(void* const* d_in, const int* in_sizes, int n_in,
                              void* d_out, int out_size, void* d_ws, size_t ws_size,
                              hipStream_t stream) {
  const float* qin = (const float*)d_in[0];
  const float* kin = (const float*)d_in[1];
  const float* vin = (const float*)d_in[2];
  const int*   msk = (const int*)d_in[3];
  const float* adj = (const float*)d_in[4];
  const float* dis = (const float*)d_in[5];
  const float* wq  = (const float*)d_in[6];
  const float* wk  = (const float*)d_in[7];
  const float* wv  = (const float*)d_in[8];
  const float* wo  = (const float*)d_in[9];
  const float* la  = (const float*)d_in[10];
  const float* ld  = (const float*)d_in[11];
  float* out = (float*)d_out;

  const size_t tensb = (size_t)BB * HH * LL * DH;   // 4,194,304
  const size_t xsz   = (size_t)BB * LL * DIN;       // 2,097,152
  unsigned short* qb  = (unsigned short*)d_ws;
  unsigned short* kb  = qb + tensb;
  unsigned short* vt  = kb + tensb;
  unsigned short* ao  = vt + tensb;                 // (B,L,512) bf16
  unsigned short* xq  = ao;                         // alias (dead until attn)
  unsigned short* xk  = ao + xsz;
  unsigned short* xv  = ao + tensb;
  unsigned short* wqb = xv + xsz;
  unsigned short* wkb = wqb + (size_t)DM * DIN;
  unsigned short* wvb = wkb + (size_t)DM * DIN;
  unsigned short* wob = wvb + (size_t)DM * DIN;
  float*          mdd = (float*)(wob + (size_t)DM * DM);
  unsigned*       bpk = (unsigned*)(mdd + (size_t)BB * LL);  // 33.5 MB packed bias

  prep<<<dim3(14984), 256, 0, stream>>>(qin, kin, vin, wq, wk, wv, wo, msk,
                                        adj, dis,
                                        xq, xk, xv, wqb, wkb, wvb, wob, mdd, bpk);
  qkv_proj<<<dim3(8, 64, 3), 256, 0, stream>>>(xq, xk, xv, wqb, wkb, wvb, qb, kb, vt);
  attn<<<dim3(1024), 256, 0, stream>>>(qb, kb, vt, mdd, bpk, la, ld, ao);
  oproj<<<dim3(8, 64), 256, 0, stream>>>(ao, wob, out);
}

// Round 5
// 278.440 us; speedup vs baseline: 1.4173x; 1.4173x over previous
//
#include <hip/hip_runtime.h>
#include <hip/hip_fp16.h>

#define BB 8
#define LL 1024
#define DIN 256
#define DM 512
#define HH 8
#define DH 64

typedef __attribute__((ext_vector_type(8))) short bf16x8;
typedef __attribute__((ext_vector_type(4))) float f32x4;

__device__ __forceinline__ unsigned short f2bf(float f) {
  union { float f; unsigned u; } c; c.f = f;
  unsigned u = c.u;
  return (unsigned short)((u + 0x7fffu + ((u >> 16) & 1u)) >> 16);
}

#if defined(__has_builtin)
#if __has_builtin(__builtin_amdgcn_cvt_pk_bf16_f32)
#define HAS_PK_BF16 1
#endif
#endif

#ifdef HAS_PK_BF16
typedef __bf16 bf2 __attribute__((ext_vector_type(2)));
__device__ __forceinline__ unsigned pk2(float lo, float hi) {
  union { bf2 v; unsigned u; } c;
  c.v = __builtin_amdgcn_cvt_pk_bf16_f32(lo, hi);
  return c.u;
}
#else
__device__ __forceinline__ unsigned pk2(float lo, float hi) {
  return ((unsigned)f2bf(hi) << 16) | f2bf(lo);
}
#endif

__device__ __forceinline__ unsigned pkh(float a, float d) {
  return (unsigned)__half_as_ushort(__float2half_rn(a)) |
         ((unsigned)__half_as_ushort(__float2half_rn(d)) << 16);
}

// ---------------- K0: merged precast ----------------
__global__ __launch_bounds__(256) void prep(
    const float* __restrict__ qin, const float* __restrict__ kin,
    const float* __restrict__ vin,
    const float* __restrict__ wq, const float* __restrict__ wk,
    const float* __restrict__ wv, const float* __restrict__ wo,
    const int* __restrict__ msk,
    const float* __restrict__ adj, const float* __restrict__ dis,
    unsigned short* __restrict__ xq, unsigned short* __restrict__ xk,
    unsigned short* __restrict__ xv,
    unsigned short* __restrict__ wqb, unsigned short* __restrict__ wkb,
    unsigned short* __restrict__ wvb, unsigned short* __restrict__ wob,
    float* __restrict__ mad, unsigned* __restrict__ bp)
{
  int t = blockIdx.x * 256 + threadIdx.x;  // quad index
  const int XS = 524288, WS = 32768;
  if (t < 3 * XS) {
    int seg = t >> 19, off = t & (XS - 1);
    const float* s = (seg == 0) ? qin : (seg == 1) ? kin : vin;
    unsigned short* d = (seg == 0) ? xq : (seg == 1) ? xk : xv;
    float4 f = ((const float4*)s)[off];
    uint2 o = { pk2(f.x, f.y), pk2(f.z, f.w) };
    ((uint2*)d)[off] = o;
    return;
  }
  t -= 3 * XS;
  if (t < 3 * WS) {
    int seg = t >> 15, off = t & (WS - 1);
    const float* s = (seg == 0) ? wq : (seg == 1) ? wk : wv;
    unsigned short* d = (seg == 0) ? wqb : (seg == 1) ? wkb : wvb;
    float4 f = ((const float4*)s)[off];
    uint2 o = { pk2(f.x, f.y), pk2(f.z, f.w) };
    ((uint2*)d)[off] = o;
    return;
  }
  t -= 3 * WS;
  if (t < 65536) {
    float4 f = ((const float4*)wo)[t];
    uint2 o = { pk2(f.x, f.y), pk2(f.z, f.w) };
    ((uint2*)wob)[t] = o;
    return;
  }
  t -= 65536;
  if (t < 2048) {
    int4 m = ((const int4*)msk)[t];
    float4 f = { m.x ? 0.0f : -30000.0f, m.y ? 0.0f : -30000.0f,
                 m.z ? 0.0f : -30000.0f, m.w ? 0.0f : -30000.0f };
    ((float4*)mad)[t] = f;
    return;
  }
  t -= 2048;  // bias pack: 2,097,152 quads
  float4 a4 = ((const float4*)adj)[t];
  float4 d4 = ((const float4*)dis)[t];
  uint4 o = { pkh(a4.x, d4.x), pkh(a4.y, d4.y), pkh(a4.z, d4.z), pkh(a4.w, d4.w) };
  ((uint4*)bp)[t] = o;
}

// ---------------- K1: QKV projection (bf16 in, bf16 out) ----------------
__global__ __launch_bounds__(256) void qkv_proj(
    const unsigned short* __restrict__ xq, const unsigned short* __restrict__ xk,
    const unsigned short* __restrict__ xv,
    const unsigned short* __restrict__ wqb, const unsigned short* __restrict__ wkb,
    const unsigned short* __restrict__ wvb,
    unsigned short* __restrict__ qb, unsigned short* __restrict__ kb,
    unsigned short* __restrict__ vt)
{
  const int t = blockIdx.z;
  const unsigned short* __restrict__ X = (t == 0) ? xq : (t == 1) ? xk : xv;
  const unsigned short* __restrict__ W = (t == 0) ? wqb : (t == 1) ? wkb : wvb;
  const int m0 = blockIdx.y * 128;
  const int h  = blockIdx.x;
  __shared__ unsigned short As[128 * 40];
  __shared__ unsigned short Bs[64 * 40];
  const int tid = threadIdx.x;
  const int wid = tid >> 6;
  const int lane = tid & 63;
  const int lo = lane & 15;
  const int quad = lane >> 4;

  f32x4 acc[2][4];
#pragma unroll
  for (int mi = 0; mi < 2; ++mi)
#pragma unroll
    for (int ni = 0; ni < 4; ++ni) acc[mi][ni] = (f32x4)0.0f;

  for (int kk = 0; kk < DIN; kk += 32) {
#pragma unroll
    for (int i = 0; i < 2; ++i) {
      int id = i * 256 + tid;
      int row = id >> 2, ch = id & 3;
      *(uint4*)&As[row * 40 + ch * 8] =
          *(const uint4*)&X[(size_t)(m0 + row) * DIN + kk + ch * 8];
    }
    {
      int row = tid >> 2, ch = tid & 3;
      *(uint4*)&Bs[row * 40 + ch * 8] =
          *(const uint4*)&W[(size_t)(h * 64 + row) * DIN + kk + ch * 8];
    }
    __syncthreads();
    bf16x8 a[2], bfr[4];
#pragma unroll
    for (int mi = 0; mi < 2; ++mi)
      a[mi] = *(const bf16x8*)&As[(wid * 32 + mi * 16 + lo) * 40 + quad * 8];
#pragma unroll
    for (int ni = 0; ni < 4; ++ni)
      bfr[ni] = *(const bf16x8*)&Bs[(ni * 16 + lo) * 40 + quad * 8];
#pragma unroll
    for (int mi = 0; mi < 2; ++mi)
#pragma unroll
      for (int ni = 0; ni < 4; ++ni)
        acc[mi][ni] = __builtin_amdgcn_mfma_f32_16x16x32_bf16(
            a[mi], bfr[ni], acc[mi][ni], 0, 0, 0);
    __syncthreads();
  }

  const int b = m0 >> 10;
  const int lbase0 = (m0 & 1023) + wid * 32;
  if (t < 2) {
    unsigned short* dstp = (t == 0) ? qb : kb;
#pragma unroll
    for (int mi = 0; mi < 2; ++mi)
#pragma unroll
      for (int ni = 0; ni < 4; ++ni) {
        int d = ni * 16 + lo;
#pragma unroll
        for (int r = 0; r < 4; ++r) {
          int lb = lbase0 + mi * 16 + quad * 4 + r;
          dstp[((size_t)(b * HH + h) * LL + lb) * DH + d] = f2bf(acc[mi][ni][r]);
        }
      }
  } else {
#pragma unroll
    for (int mi = 0; mi < 2; ++mi)
#pragma unroll
      for (int ni = 0; ni < 4; ++ni) {
        int d = ni * 16 + lo;
        int lb = lbase0 + mi * 16 + quad * 4;
        uint2 o = { pk2(acc[mi][ni][0], acc[mi][ni][1]),
                    pk2(acc[mi][ni][2], acc[mi][ni][3]) };
        *(uint2*)&vt[((size_t)(b * HH + h) * DH + d) * LL + lb] = o;
      }
  }
}

// ---------------- K2: fused biased attention, LDS-staged, barrier-pipelined --
// grid 1024: idx = qt*32 + hg*8 + b (XCD swizzle). 4 waves/block:
// (h = hg*2 + wid&1, K-half = wid>>1). Per 32-k tile: all waves stage
// K/V^T/bias/mask into LDS (XOR-swizzled 16B chunks, conflict-free),
// 2 barriers/tile -> all loads batched, drains overlap across 3 blocks/CU.
__global__ __launch_bounds__(256) void attn(
    const unsigned short* __restrict__ qb, const unsigned short* __restrict__ kb,
    const unsigned short* __restrict__ vt,
    const float* __restrict__ mad, const unsigned* __restrict__ bp,
    const float* __restrict__ la_, const float* __restrict__ ld_,
    unsigned short* __restrict__ ao)
{
  const int bi = blockIdx.x;
  const int b  = bi & 7;
  const int hg = (bi >> 3) & 3;
  const int q0 = (bi >> 5) * 32;
  const int tid = threadIdx.x;
  const int wid = tid >> 6;
  const int lane = tid & 63;
  const int lo = lane & 15;
  const int quad = lane >> 4;
  const int h  = hg * 2 + (wid & 1);
  const int kh = wid >> 1;
  const int bh = b * HH + h;

  // LDS arena: kbuf 16K | vbuf 16K | bbuf 8K | mask 256B | pbuf 10240B = 51456B
  __shared__ __align__(16) char arena[51456];
  unsigned short* kbufw = (unsigned short*)(arena) + wid * 2048;           // 32 rows x 64
  unsigned short* vbufw = (unsigned short*)(arena + 16384) + wid * 2048;   // 64 rows x 32
  unsigned*       bbuf  = (unsigned*)(arena + 32768);                      // [2][32 x 32]
  float*          mkbuf = (float*)(arena + 40960);                         // [2][32]
  unsigned short* pbufw = (unsigned short*)(arena + 41216) + wid * 1280;   // 32 x 40
  float*          mgbuf = (float*)arena;                                   // merge alias

  const float LOG2E = 1.44269504f;
  const float la2 = la_[h] * LOG2E, ld2 = ld_[h] * LOG2E;
  const float sc2 = 0.125f * LOG2E;

  const unsigned short* qp = qb + ((size_t)bh * LL + q0) * DH;
  bf16x8 qB[2][2];
#pragma unroll
  for (int nj = 0; nj < 2; ++nj)
#pragma unroll
    for (int ki = 0; ki < 2; ++ki)
      qB[nj][ki] = *(const bf16x8*)&qp[(nj * 16 + lo) * DH + ki * 32 + quad * 8];

  const unsigned short* kp = kb + (size_t)bh * LL * DH;
  const unsigned short* vp = vt + (size_t)bh * DH * LL;
  const unsigned* bpp = bp + ((size_t)b * LL + q0) * LL;
  const float* mp = mad + b * LL;

  f32x4 o[4][2];
  float rs[2] = {0.0f, 0.0f};
#pragma unroll
  for (int md = 0; md < 4; ++md)
#pragma unroll
    for (int nj = 0; nj < 2; ++nj) o[md][nj] = (f32x4)0.0f;

  const int kbeg = kh * (LL / 2);
  const int r8 = lane >> 3, p8 = lane & 7;   // 8-chunk stagers (K, bias)
  const int r4 = lane >> 2, p4 = lane & 3;   // 4-chunk stager (V)

  for (int jt = 0; jt < 16; ++jt) {
    const int k0 = kbeg + jt * 32;

    // ---- stage: all global loads for this tile issue together ----
    {
      const unsigned short* kg = kp + (size_t)k0 * DH;
#pragma unroll
      for (int j = 0; j < 4; ++j) {
        int row = j * 8 + r8;
        uint4 tv = *(const uint4*)&kg[row * 64 + ((p8 ^ r8) * 8)];
        *(uint4*)&kbufw[row * 64 + p8 * 8] = tv;
      }
      const unsigned short* vg = vp + k0;
#pragma unroll
      for (int j = 0; j < 4; ++j) {
        int row = j * 16 + r4;
        uint4 tv = *(const uint4*)&vg[(size_t)row * LL + ((p4 ^ ((r4 >> 1) & 3)) * 8)];
        *(uint4*)&vbufw[row * 32 + p4 * 8] = tv;
      }
      if ((wid & 1) == 0) {       // waves 0,2 stage bias for half kh = wid>>1
        const int khs = wid >> 1;
        const unsigned* bg = bpp + khs * (LL / 2) + jt * 32;
#pragma unroll
        for (int j = 0; j < 4; ++j) {
          int row = j * 8 + r8;
          uint4 tv = *(const uint4*)&bg[(size_t)row * LL + ((p8 ^ r8) * 4)];
          *(uint4*)&bbuf[khs * 1024 + row * 32 + p8 * 4] = tv;
        }
      } else if (wid == 1 && lane < 16) {  // mask: both halves, 256 B
        float4 tv = *(const float4*)&mp[(lane >> 3) * (LL / 2) + jt * 32 + (lane & 7) * 4];
        *(float4*)&mkbuf[(lane >> 3) * 32 + (lane & 7) * 4] = tv;
      }
    }
    __syncthreads();

    // ---- consume ----
    bf16x8 kA[2][2];
#pragma unroll
    for (int mi = 0; mi < 2; ++mi)
#pragma unroll
      for (int ki = 0; ki < 2; ++ki)
        kA[mi][ki] = *(const bf16x8*)&kbufw[(mi * 16 + lo) * 64 +
                                            (((ki * 4 + quad) ^ (lo & 7)) * 8)];
    f32x4 s[2][2];
#pragma unroll
    for (int mi = 0; mi < 2; ++mi)
#pragma unroll
      for (int nj = 0; nj < 2; ++nj) s[mi][nj] = (f32x4)0.0f;
#pragma unroll
    for (int ki = 0; ki < 2; ++ki)
#pragma unroll
      for (int mi = 0; mi < 2; ++mi)
#pragma unroll
        for (int nj = 0; nj < 2; ++nj)
          s[mi][nj] = __builtin_amdgcn_mfma_f32_16x16x32_bf16(
              kA[mi][ki], qB[nj][ki], s[mi][nj], 0, 0, 0);

    f32x4 msv[2];
#pragma unroll
    for (int mi = 0; mi < 2; ++mi)
      msv[mi] = *(const f32x4*)&mkbuf[kh * 32 + mi * 16 + quad * 4];

#pragma unroll
    for (int mi = 0; mi < 2; ++mi)
#pragma unroll
      for (int nj = 0; nj < 2; ++nj) {
        uint4 u = *(const uint4*)&bbuf[kh * 1024 + (nj * 16 + lo) * 32 +
                                       (((mi * 4 + quad) ^ (lo & 7)) * 4)];
        float p[4];
#pragma unroll
        for (int r = 0; r < 4; ++r) {
          union { unsigned v; __half2 hh; } c; c.v = u[r];
          float tt = fmaf(__high2float(c.hh), ld2, msv[mi][r]);
          tt = fmaf(__low2float(c.hh), la2, tt);
          p[r] = __builtin_amdgcn_exp2f(fmaf(s[mi][nj][r], sc2, tt));
        }
        rs[nj] += (p[0] + p[1]) + (p[2] + p[3]);
        uint2 w = { pk2(p[0], p[1]), pk2(p[2], p[3]) };
        *(uint2*)&pbufw[(nj * 16 + lo) * 40 + mi * 16 + quad * 4] = w;
      }

    asm volatile("s_waitcnt lgkmcnt(0)" ::: "memory");

    bf16x8 pB[2];
#pragma unroll
    for (int nj = 0; nj < 2; ++nj)
      pB[nj] = *(const bf16x8*)&pbufw[(nj * 16 + lo) * 40 + quad * 8];

    bf16x8 vA[4];
#pragma unroll
    for (int md = 0; md < 4; ++md)
      vA[md] = *(const bf16x8*)&vbufw[(md * 16 + lo) * 32 +
                                      ((quad ^ ((lo >> 1) & 3)) * 8)];
#pragma unroll
    for (int md = 0; md < 4; ++md)
#pragma unroll
      for (int nj = 0; nj < 2; ++nj)
        o[md][nj] = __builtin_amdgcn_mfma_f32_16x16x32_bf16(
            vA[md], pB[nj], o[md][nj], 0, 0, 0);

    __syncthreads();
  }

  // merge the two K-halves (mgbuf aliases stage buffers, dead now)
  const int hs = wid & 1;
  if (kh == 1) {
#pragma unroll
    for (int md = 0; md < 4; ++md)
#pragma unroll
      for (int nj = 0; nj < 2; ++nj)
#pragma unroll
        for (int r = 0; r < 4; ++r)
          mgbuf[hs * 2176 + ((md * 2 + nj) * 4 + r) * 64 + lane] = o[md][nj][r];
    mgbuf[hs * 2176 + 32 * 64 + lane] = rs[0];
    mgbuf[hs * 2176 + 33 * 64 + lane] = rs[1];
  }
  __syncthreads();
  if (kh == 0) {
#pragma unroll
    for (int md = 0; md < 4; ++md)
#pragma unroll
      for (int nj = 0; nj < 2; ++nj)
#pragma unroll
        for (int r = 0; r < 4; ++r)
          o[md][nj][r] += mgbuf[hs * 2176 + ((md * 2 + nj) * 4 + r) * 64 + lane];
    rs[0] += mgbuf[hs * 2176 + 32 * 64 + lane];
    rs[1] += mgbuf[hs * 2176 + 33 * 64 + lane];
    float inv[2];
#pragma unroll
    for (int nj = 0; nj < 2; ++nj) {
      rs[nj] += __shfl_xor(rs[nj], 16);
      rs[nj] += __shfl_xor(rs[nj], 32);
      inv[nj] = __builtin_amdgcn_rcpf(rs[nj]);
    }
#pragma unroll
    for (int md = 0; md < 4; ++md)
#pragma unroll
      for (int nj = 0; nj < 2; ++nj) {
        int l = q0 + nj * 16 + lo;
        uint2 st = { pk2(o[md][nj][0] * inv[nj], o[md][nj][1] * inv[nj]),
                     pk2(o[md][nj][2] * inv[nj], o[md][nj][3] * inv[nj]) };
        *(uint2*)&ao[((size_t)b * LL + l) * DM + h * DH + md * 16 + quad * 4] = st;
      }
  }
}

// ---------------- K3: output projection ----------------
__global__ __launch_bounds__(256) void oproj(
    const unsigned short* __restrict__ ao, const unsigned short* __restrict__ wob,
    float* __restrict__ out)
{
  const int m0 = blockIdx.y * 128;
  const int n0 = blockIdx.x * 64;
  __shared__ unsigned short As[128 * 40];
  __shared__ unsigned short Bs[64 * 40];
  const int tid = threadIdx.x;
  const int wid = tid >> 6;
  const int lane = tid & 63;
  const int lo = lane & 15;
  const int quad = lane >> 4;

  f32x4 acc[2][4];
#pragma unroll
  for (int mi = 0; mi < 2; ++mi)
#pragma unroll
    for (int ni = 0; ni < 4; ++ni) acc[mi][ni] = (f32x4)0.0f;

  for (int kk = 0; kk < DM; kk += 32) {
#pragma unroll
    for (int i = 0; i < 2; ++i) {
      int id = i * 256 + tid;
      int row = id >> 2, ch = id & 3;
      *(uint4*)&As[row * 40 + ch * 8] =
          *(const uint4*)&ao[(size_t)(m0 + row) * DM + kk + ch * 8];
    }
    {
      int row = tid >> 2, ch = tid & 3;
      *(uint4*)&Bs[row * 40 + ch * 8] =
          *(const uint4*)&wob[(size_t)(n0 + row) * DM + kk + ch * 8];
    }
    __syncthreads();
    bf16x8 a[2], bfr[4];
#pragma unroll
    for (int mi = 0; mi < 2; ++mi)
      a[mi] = *(const bf16x8*)&As[(wid * 32 + mi * 16 + lo) * 40 + quad * 8];
#pragma unroll
    for (int ni = 0; ni < 4; ++ni)
      bfr[ni] = *(const bf16x8*)&Bs[(ni * 16 + lo) * 40 + quad * 8];
#pragma unroll
    for (int mi = 0; mi < 2; ++mi)
#pragma unroll
      for (int ni = 0; ni < 4; ++ni)
        acc[mi][ni] = __builtin_amdgcn_mfma_f32_16x16x32_bf16(
            a[mi], bfr[ni], acc[mi][ni], 0, 0, 0);
    __syncthreads();
  }

#pragma unroll
  for (int mi = 0; mi < 2; ++mi)
#pragma unroll
    for (int ni = 0; ni < 4; ++ni)
#pragma unroll
      for (int r = 0; r < 4; ++r)
        out[(size_t)(m0 + wid * 32 + mi * 16 + quad * 4 + r) * DM +
            n0 + ni * 16 + lo] = acc[mi][ni][r];
}

extern "C" void kernel_launch(void* const* d_in, const int* in_sizes, int n_in,
                              void* d_out, int out_size, void* d_ws, size_t ws_size,
                              hipStream_t stream) {
  const float* qin = (const float*)d_in[0];
  const float* kin = (const float*)d_in[1];
  const float* vin = (const float*)d_in[2];
  const int*   msk = (const int*)d_in[3];
  const float* adj = (const float*)d_in[4];
  const float* dis = (const float*)d_in[5];
  const float* wq  = (const float*)d_in[6];
  const float* wk  = (const float*)d_in[7];
  const float* wv  = (const float*)d_in[8];
  const float* wo  = (const float*)d_in[9];
  const float* la  = (const float*)d_in[10];
  const float* ld  = (const float*)d_in[11];
  float* out = (float*)d_out;

  const size_t tensb = (size_t)BB * HH * LL * DH;   // 4,194,304
  const size_t xsz   = (size_t)BB * LL * DIN;       // 2,097,152
  unsigned short* qb  = (unsigned short*)d_ws;
  unsigned short* kb  = qb + tensb;
  unsigned short* vt  = kb + tensb;
  unsigned short* ao  = vt + tensb;                 // (B,L,512) bf16
  unsigned short* xq  = ao;                         // alias (dead until attn)
  unsigned short* xk  = ao + xsz;
  unsigned short* xv  = ao + tensb;
  unsigned short* wqb = xv + xsz;
  unsigned short* wkb = wqb + (size_t)DM * DIN;
  unsigned short* wvb = wkb + (size_t)DM * DIN;
  unsigned short* wob = wvb + (size_t)DM * DIN;
  float*          mdd = (float*)(wob + (size_t)DM * DM);
  unsigned*       bpk = (unsigned*)(mdd + (size_t)BB * LL);  // 33.5 MB packed bias

  prep<<<dim3(14984), 256, 0, stream>>>(qin, kin, vin, wq, wk, wv, wo, msk,
                                        adj, dis,
                                        xq, xk, xv, wqb, wkb, wvb, wob, mdd, bpk);
  qkv_proj<<<dim3(8, 64, 3), 256, 0, stream>>>(xq, xk, xv, wqb, wkb, wvb, qb, kb, vt);
  attn<<<dim3(1024), 256, 0, stream>>>(qb, kb, vt, mdd, bpk, la, ld, ao);
  oproj<<<dim3(8, 64), 256, 0, stream>>>(ao, wob, out);
}

// Round 6
// 245.577 us; speedup vs baseline: 1.6070x; 1.1338x over previous
//
#include <hip/hip_runtime.h>
#include <hip/hip_fp16.h>

#define BB 8
#define LL 1024
#define DIN 256
#define DM 512
#define HH 8
#define DH 64

typedef __attribute__((ext_vector_type(8))) short bf16x8;
typedef __attribute__((ext_vector_type(4))) float f32x4;

__device__ __forceinline__ unsigned short f2bf(float f) {
  union { float f; unsigned u; } c; c.f = f;
  unsigned u = c.u;
  return (unsigned short)((u + 0x7fffu + ((u >> 16) & 1u)) >> 16);
}

#if defined(__has_builtin)
#if __has_builtin(__builtin_amdgcn_cvt_pk_bf16_f32)
#define HAS_PK_BF16 1
#endif
#endif

#ifdef HAS_PK_BF16
typedef __bf16 bf2 __attribute__((ext_vector_type(2)));
__device__ __forceinline__ unsigned pk2(float lo, float hi) {
  union { bf2 v; unsigned u; } c;
  c.v = __builtin_amdgcn_cvt_pk_bf16_f32(lo, hi);
  return c.u;
}
#else
__device__ __forceinline__ unsigned pk2(float lo, float hi) {
  return ((unsigned)f2bf(hi) << 16) | f2bf(lo);
}
#endif

__device__ __forceinline__ unsigned pkh(float a, float d) {
  return (unsigned)__half_as_ushort(__float2half_rn(a)) |
         ((unsigned)__half_as_ushort(__float2half_rn(d)) << 16);
}

// async global -> LDS DMA, 16 B per lane; LDS dest = wave-uniform base + lane*16
__device__ __forceinline__ void async_copy16(void* lds, const void* g) {
  __builtin_amdgcn_global_load_lds(
      (const __attribute__((address_space(1))) unsigned*)g,
      (__attribute__((address_space(3))) unsigned*)lds, 16, 0, 0);
}

// ---------------- K0: merged precast ----------------
__global__ __launch_bounds__(256) void prep(
    const float* __restrict__ qin, const float* __restrict__ kin,
    const float* __restrict__ vin,
    const float* __restrict__ wq, const float* __restrict__ wk,
    const float* __restrict__ wv, const float* __restrict__ wo,
    const int* __restrict__ msk,
    const float* __restrict__ adj, const float* __restrict__ dis,
    unsigned short* __restrict__ xq, unsigned short* __restrict__ xk,
    unsigned short* __restrict__ xv,
    unsigned short* __restrict__ wqb, unsigned short* __restrict__ wkb,
    unsigned short* __restrict__ wvb, unsigned short* __restrict__ wob,
    float* __restrict__ mad, unsigned* __restrict__ bp)
{
  int t = blockIdx.x * 256 + threadIdx.x;  // quad index
  const int XS = 524288, WS = 32768;
  if (t < 3 * XS) {
    int seg = t >> 19, off = t & (XS - 1);
    const float* s = (seg == 0) ? qin : (seg == 1) ? kin : vin;
    unsigned short* d = (seg == 0) ? xq : (seg == 1) ? xk : xv;
    float4 f = ((const float4*)s)[off];
    uint2 o = { pk2(f.x, f.y), pk2(f.z, f.w) };
    ((uint2*)d)[off] = o;
    return;
  }
  t -= 3 * XS;
  if (t < 3 * WS) {
    int seg = t >> 15, off = t & (WS - 1);
    const float* s = (seg == 0) ? wq : (seg == 1) ? wk : wv;
    unsigned short* d = (seg == 0) ? wqb : (seg == 1) ? wkb : wvb;
    float4 f = ((const float4*)s)[off];
    uint2 o = { pk2(f.x, f.y), pk2(f.z, f.w) };
    ((uint2*)d)[off] = o;
    return;
  }
  t -= 3 * WS;
  if (t < 65536) {
    float4 f = ((const float4*)wo)[t];
    uint2 o = { pk2(f.x, f.y), pk2(f.z, f.w) };
    ((uint2*)wob)[t] = o;
    return;
  }
  t -= 65536;
  if (t < 2048) {
    int4 m = ((const int4*)msk)[t];
    float4 f = { m.x ? 0.0f : -30000.0f, m.y ? 0.0f : -30000.0f,
                 m.z ? 0.0f : -30000.0f, m.w ? 0.0f : -30000.0f };
    ((float4*)mad)[t] = f;
    return;
  }
  t -= 2048;  // bias pack: 2,097,152 quads
  float4 a4 = ((const float4*)adj)[t];
  float4 d4 = ((const float4*)dis)[t];
  uint4 o = { pkh(a4.x, d4.x), pkh(a4.y, d4.y), pkh(a4.z, d4.z), pkh(a4.w, d4.w) };
  ((uint4*)bp)[t] = o;
}

// ---------------- K1: QKV projection (bf16 in, bf16 out) ----------------
__global__ __launch_bounds__(256) void qkv_proj(
    const unsigned short* __restrict__ xq, const unsigned short* __restrict__ xk,
    const unsigned short* __restrict__ xv,
    const unsigned short* __restrict__ wqb, const unsigned short* __restrict__ wkb,
    const unsigned short* __restrict__ wvb,
    unsigned short* __restrict__ qb, unsigned short* __restrict__ kb,
    unsigned short* __restrict__ vt)
{
  const int t = blockIdx.z;
  const unsigned short* __restrict__ X = (t == 0) ? xq : (t == 1) ? xk : xv;
  const unsigned short* __restrict__ W = (t == 0) ? wqb : (t == 1) ? wkb : wvb;
  const int m0 = blockIdx.y * 128;
  const int h  = blockIdx.x;
  __shared__ unsigned short As[128 * 40];
  __shared__ unsigned short Bs[64 * 40];
  const int tid = threadIdx.x;
  const int wid = tid >> 6;
  const int lane = tid & 63;
  const int lo = lane & 15;
  const int quad = lane >> 4;

  f32x4 acc[2][4];
#pragma unroll
  for (int mi = 0; mi < 2; ++mi)
#pragma unroll
    for (int ni = 0; ni < 4; ++ni) acc[mi][ni] = (f32x4)0.0f;

  for (int kk = 0; kk < DIN; kk += 32) {
#pragma unroll
    for (int i = 0; i < 2; ++i) {
      int id = i * 256 + tid;
      int row = id >> 2, ch = id & 3;
      *(uint4*)&As[row * 40 + ch * 8] =
          *(const uint4*)&X[(size_t)(m0 + row) * DIN + kk + ch * 8];
    }
    {
      int row = tid >> 2, ch = tid & 3;
      *(uint4*)&Bs[row * 40 + ch * 8] =
          *(const uint4*)&W[(size_t)(h * 64 + row) * DIN + kk + ch * 8];
    }
    __syncthreads();
    bf16x8 a[2], bfr[4];
#pragma unroll
    for (int mi = 0; mi < 2; ++mi)
      a[mi] = *(const bf16x8*)&As[(wid * 32 + mi * 16 + lo) * 40 + quad * 8];
#pragma unroll
    for (int ni = 0; ni < 4; ++ni)
      bfr[ni] = *(const bf16x8*)&Bs[(ni * 16 + lo) * 40 + quad * 8];
#pragma unroll
    for (int mi = 0; mi < 2; ++mi)
#pragma unroll
      for (int ni = 0; ni < 4; ++ni)
        acc[mi][ni] = __builtin_amdgcn_mfma_f32_16x16x32_bf16(
            a[mi], bfr[ni], acc[mi][ni], 0, 0, 0);
    __syncthreads();
  }

  const int b = m0 >> 10;
  const int lbase0 = (m0 & 1023) + wid * 32;
  if (t < 2) {
    unsigned short* dstp = (t == 0) ? qb : kb;
#pragma unroll
    for (int mi = 0; mi < 2; ++mi)
#pragma unroll
      for (int ni = 0; ni < 4; ++ni) {
        int d = ni * 16 + lo;
#pragma unroll
        for (int r = 0; r < 4; ++r) {
          int lb = lbase0 + mi * 16 + quad * 4 + r;
          dstp[((size_t)(b * HH + h) * LL + lb) * DH + d] = f2bf(acc[mi][ni][r]);
        }
      }
  } else {
#pragma unroll
    for (int mi = 0; mi < 2; ++mi)
#pragma unroll
      for (int ni = 0; ni < 4; ++ni) {
        int d = ni * 16 + lo;
        int lb = lbase0 + mi * 16 + quad * 4;
        uint2 o = { pk2(acc[mi][ni][0], acc[mi][ni][1]),
                    pk2(acc[mi][ni][2], acc[mi][ni][3]) };
        *(uint2*)&vt[((size_t)(b * HH + h) * DH + d) * LL + lb] = o;
      }
  }
}

// ---------------- K2: fused biased attention, async-DMA staged ----------
// grid 1024: idx = qt*32 + hg*8 + b (XCD swizzle). 4 waves/block:
// (h = hg*2 + wid&1, K-half = wid>>1). Per 32-k tile: K + packed bias
// staged via global_load_lds DMA (source XOR-swizzled so the LDS image is
// conflict-free); V + mask direct to VGPR. 34.8 KB LDS -> 4 blocks/CU.
__global__ __launch_bounds__(256) void attn(
    const unsigned short* __restrict__ qb, const unsigned short* __restrict__ kb,
    const unsigned short* __restrict__ vt,
    const float* __restrict__ mad, const unsigned* __restrict__ bp,
    const float* __restrict__ la_, const float* __restrict__ ld_,
    unsigned short* __restrict__ ao)
{
  const int bi = blockIdx.x;
  const int b  = bi & 7;
  const int hg = (bi >> 3) & 3;
  const int q0 = (bi >> 5) * 32;
  const int tid = threadIdx.x;
  const int wid = tid >> 6;
  const int lane = tid & 63;
  const int lo = lane & 15;
  const int quad = lane >> 4;
  const int h  = hg * 2 + (wid & 1);
  const int kh = wid >> 1;
  const int bh = b * HH + h;

  // arena: kbuf 16K | bbuf 8K | pbuf 10240 = 34816 B -> 4 blocks/CU
  __shared__ __align__(16) char arena[34816];
  unsigned short* kbufw = (unsigned short*)(arena) + wid * 2048;          // 32 x 64
  unsigned*       bbuf  = (unsigned*)(arena + 16384);                     // [2][32 x 32]
  unsigned short* pbufw = (unsigned short*)(arena + 24576) + wid * 1280;  // 32 x 40
  float*          mgbuf = (float*)arena;                                  // merge alias

  const float LOG2E = 1.44269504f;
  const float la2 = la_[h] * LOG2E, ld2 = ld_[h] * LOG2E;
  const float sc2 = 0.125f * LOG2E;

  const unsigned short* qp = qb + ((size_t)bh * LL + q0) * DH;
  bf16x8 qB[2][2];
#pragma unroll
  for (int nj = 0; nj < 2; ++nj)
#pragma unroll
    for (int ki = 0; ki < 2; ++ki)
      qB[nj][ki] = *(const bf16x8*)&qp[(nj * 16 + lo) * DH + ki * 32 + quad * 8];

  const unsigned short* kp = kb + (size_t)bh * LL * DH;
  const unsigned short* vp = vt + (size_t)bh * DH * LL;
  const unsigned* bpp = bp + ((size_t)b * LL + q0) * LL;
  const float* mp = mad + b * LL;

  f32x4 o[4][2];
  float rs[2] = {0.0f, 0.0f};
#pragma unroll
  for (int md = 0; md < 4; ++md)
#pragma unroll
    for (int nj = 0; nj < 2; ++nj) o[md][nj] = (f32x4)0.0f;

  const int kbeg = kh * (LL / 2);
  const int r8 = lane >> 3, p8 = lane & 7;

  for (int jt = 0; jt < 16; ++jt) {
    const int k0 = kbeg + jt * 32;

    // ---- stage: async DMA (K, bias) + direct VGPR (V, mask) ----
    {
      const unsigned short* kg = kp + (size_t)k0 * DH;
#pragma unroll
      for (int j = 0; j < 4; ++j)
        async_copy16(kbufw + j * 512,
                     kg + (j * 8 + r8) * 64 + ((p8 ^ r8) * 8));
      if ((wid & 1) == 0) {  // waves 0,2 stage bias for half khs
        const int khs = wid >> 1;
        const unsigned* bg = bpp + khs * (LL / 2) + jt * 32;
        unsigned* bb = bbuf + khs * 1024;
#pragma unroll
        for (int j = 0; j < 4; ++j)
          async_copy16(bb + j * 256,
                       bg + (size_t)(j * 8 + r8) * LL + ((p8 ^ r8) * 4));
      }
    }
    bf16x8 vA[4];
#pragma unroll
    for (int md = 0; md < 4; ++md)
      vA[md] = *(const bf16x8*)&vp[(md * 16 + lo) * LL + k0 + quad * 8];
    f32x4 msv[2];
#pragma unroll
    for (int mi = 0; mi < 2; ++mi)
      msv[mi] = *(const f32x4*)&mp[k0 + mi * 16 + quad * 4];

    __syncthreads();

    // ---- consume ----
    bf16x8 kA[2][2];
#pragma unroll
    for (int mi = 0; mi < 2; ++mi)
#pragma unroll
      for (int ki = 0; ki < 2; ++ki)
        kA[mi][ki] = *(const bf16x8*)&kbufw[(mi * 16 + lo) * 64 +
                                            (((ki * 4 + quad) ^ (lo & 7)) * 8)];
    f32x4 s[2][2];
#pragma unroll
    for (int mi = 0; mi < 2; ++mi)
#pragma unroll
      for (int nj = 0; nj < 2; ++nj) s[mi][nj] = (f32x4)0.0f;
#pragma unroll
    for (int ki = 0; ki < 2; ++ki)
#pragma unroll
      for (int mi = 0; mi < 2; ++mi)
#pragma unroll
        for (int nj = 0; nj < 2; ++nj)
          s[mi][nj] = __builtin_amdgcn_mfma_f32_16x16x32_bf16(
              kA[mi][ki], qB[nj][ki], s[mi][nj], 0, 0, 0);

#pragma unroll
    for (int mi = 0; mi < 2; ++mi)
#pragma unroll
      for (int nj = 0; nj < 2; ++nj) {
        uint4 u = *(const uint4*)&bbuf[kh * 1024 + (nj * 16 + lo) * 32 +
                                       (((mi * 4 + quad) ^ (lo & 7)) * 4)];
        float p[4];
#pragma unroll
        for (int r = 0; r < 4; ++r) {
          union { unsigned v; __half2 hh; } c; c.v = u[r];
          float tt = fmaf(__high2float(c.hh), ld2, msv[mi][r]);
          tt = fmaf(__low2float(c.hh), la2, tt);
          p[r] = __builtin_amdgcn_exp2f(fmaf(s[mi][nj][r], sc2, tt));
        }
        rs[nj] += (p[0] + p[1]) + (p[2] + p[3]);
        uint2 w = { pk2(p[0], p[1]), pk2(p[2], p[3]) };
        *(uint2*)&pbufw[(nj * 16 + lo) * 40 + mi * 16 + quad * 4] = w;
      }

    asm volatile("s_waitcnt lgkmcnt(0)" ::: "memory");

    bf16x8 pB[2];
#pragma unroll
    for (int nj = 0; nj < 2; ++nj)
      pB[nj] = *(const bf16x8*)&pbufw[(nj * 16 + lo) * 40 + quad * 8];

#pragma unroll
    for (int md = 0; md < 4; ++md)
#pragma unroll
      for (int nj = 0; nj < 2; ++nj)
        o[md][nj] = __builtin_amdgcn_mfma_f32_16x16x32_bf16(
            vA[md], pB[nj], o[md][nj], 0, 0, 0);

    __syncthreads();
  }

  // merge the two K-halves (mgbuf aliases stage buffers, dead now)
  const int hs = wid & 1;
  if (kh == 1) {
#pragma unroll
    for (int md = 0; md < 4; ++md)
#pragma unroll
      for (int nj = 0; nj < 2; ++nj)
#pragma unroll
        for (int r = 0; r < 4; ++r)
          mgbuf[hs * 2176 + ((md * 2 + nj) * 4 + r) * 64 + lane] = o[md][nj][r];
    mgbuf[hs * 2176 + 32 * 64 + lane] = rs[0];
    mgbuf[hs * 2176 + 33 * 64 + lane] = rs[1];
  }
  __syncthreads();
  if (kh == 0) {
#pragma unroll
    for (int md = 0; md < 4; ++md)
#pragma unroll
      for (int nj = 0; nj < 2; ++nj)
#pragma unroll
        for (int r = 0; r < 4; ++r)
          o[md][nj][r] += mgbuf[hs * 2176 + ((md * 2 + nj) * 4 + r) * 64 + lane];
    rs[0] += mgbuf[hs * 2176 + 32 * 64 + lane];
    rs[1] += mgbuf[hs * 2176 + 33 * 64 + lane];
    float inv[2];
#pragma unroll
    for (int nj = 0; nj < 2; ++nj) {
      rs[nj] += __shfl_xor(rs[nj], 16);
      rs[nj] += __shfl_xor(rs[nj], 32);
      inv[nj] = __builtin_amdgcn_rcpf(rs[nj]);
    }
#pragma unroll
    for (int md = 0; md < 4; ++md)
#pragma unroll
      for (int nj = 0; nj < 2; ++nj) {
        int l = q0 + nj * 16 + lo;
        uint2 st = { pk2(o[md][nj][0] * inv[nj], o[md][nj][1] * inv[nj]),
                     pk2(o[md][nj][2] * inv[nj], o[md][nj][3] * inv[nj]) };
        *(uint2*)&ao[((size_t)b * LL + l) * DM + h * DH + md * 16 + quad * 4] = st;
      }
  }
}

// ---------------- K3: output projection ----------------
__global__ __launch_bounds__(256) void oproj(
    const unsigned short* __restrict__ ao, const unsigned short* __restrict__ wob,
    float* __restrict__ out)
{
  const int m0 = blockIdx.y * 128;
  const int n0 = blockIdx.x * 64;
  __shared__ unsigned short As[128 * 40];
  __shared__ unsigned short Bs[64 * 40];
  const int tid = threadIdx.x;
  const int wid = tid >> 6;
  const int lane = tid & 63;
  const int lo = lane & 15;
  const int quad = lane >> 4;

  f32x4 acc[2][4];
#pragma unroll
  for (int mi = 0; mi < 2; ++mi)
#pragma unroll
    for (int ni = 0; ni < 4; ++ni) acc[mi][ni] = (f32x4)0.0f;

  for (int kk = 0; kk < DM; kk += 32) {
#pragma unroll
    for (int i = 0; i < 2; ++i) {
      int id = i * 256 + tid;
      int row = id >> 2, ch = id & 3;
      *(uint4*)&As[row * 40 + ch * 8] =
          *(const uint4*)&ao[(size_t)(m0 + row) * DM + kk + ch * 8];
    }
    {
      int row = tid >> 2, ch = tid & 3;
      *(uint4*)&Bs[row * 40 + ch * 8] =
          *(const uint4*)&wob[(size_t)(n0 + row) * DM + kk + ch * 8];
    }
    __syncthreads();
    bf16x8 a[2], bfr[4];
#pragma unroll
    for (int mi = 0; mi < 2; ++mi)
      a[mi] = *(const bf16x8*)&As[(wid * 32 + mi * 16 + lo) * 40 + quad * 8];
#pragma unroll
    for (int ni = 0; ni < 4; ++ni)
      bfr[ni] = *(const bf16x8*)&Bs[(ni * 16 + lo) * 40 + quad * 8];
#pragma unroll
    for (int mi = 0; mi < 2; ++mi)
#pragma unroll
      for (int ni = 0; ni < 4; ++ni)
        acc[mi][ni] = __builtin_amdgcn_mfma_f32_16x16x32_bf16(
            a[mi], bfr[ni], acc[mi][ni], 0, 0, 0);
    __syncthreads();
  }

#pragma unroll
  for (int mi = 0; mi < 2; ++mi)
#pragma unroll
    for (int ni = 0; ni < 4; ++ni)
#pragma unroll
      for (int r = 0; r < 4; ++r)
        out[(size_t)(m0 + wid * 32 + mi * 16 + quad * 4 + r) * DM +
            n0 + ni * 16 + lo] = acc[mi][ni][r];
}

extern "C" void kernel_launch(void* const* d_in, const int* in_sizes, int n_in,
                              void* d_out, int out_size, void* d_ws, size_t ws_size,
                              hipStream_t stream) {
  const float* qin = (const float*)d_in[0];
  const float* kin = (const float*)d_in[1];
  const float* vin = (const float*)d_in[2];
  const int*   msk = (const int*)d_in[3];
  const float* adj = (const float*)d_in[4];
  const float* dis = (const float*)d_in[5];
  const float* wq  = (const float*)d_in[6];
  const float* wk  = (const float*)d_in[7];
  const float* wv  = (const float*)d_in[8];
  const float* wo  = (const float*)d_in[9];
  const float* la  = (const float*)d_in[10];
  const float* ld  = (const float*)d_in[11];
  float* out = (float*)d_out;

  const size_t tensb = (size_t)BB * HH * LL * DH;   // 4,194,304
  const size_t xsz   = (size_t)BB * LL * DIN;       // 2,097,152
  unsigned short* qb  = (unsigned short*)d_ws;
  unsigned short* kb  = qb + tensb;
  unsigned short* vt  = kb + tensb;
  unsigned short* ao  = vt + tensb;                 // (B,L,512) bf16
  unsigned short* xq  = ao;                         // alias (dead until attn)
  unsigned short* xk  = ao + xsz;
  unsigned short* xv  = ao + tensb;
  unsigned short* wqb = xv + xsz;
  unsigned short* wkb = wqb + (size_t)DM * DIN;
  unsigned short* wvb = wkb + (size_t)DM * DIN;
  unsigned short* wob = wvb + (size_t)DM * DIN;
  float*          mdd = (float*)(wob + (size_t)DM * DM);
  unsigned*       bpk = (unsigned*)(mdd + (size_t)BB * LL);  // 33.5 MB packed bias

  prep<<<dim3(14984), 256, 0, stream>>>(qin, kin, vin, wq, wk, wv, wo, msk,
                                        adj, dis,
                                        xq, xk, xv, wqb, wkb, wvb, wob, mdd, bpk);
  qkv_proj<<<dim3(8, 64, 3), 256, 0, stream>>>(xq, xk, xv, wqb, wkb, wvb, qb, kb, vt);
  attn<<<dim3(1024), 256, 0, stream>>>(qb, kb, vt, mdd, bpk, la, ld, ao);
  oproj<<<dim3(8, 64), 256, 0, stream>>>(ao, wob, out);
}

// Round 7
// 233.873 us; speedup vs baseline: 1.6874x; 1.0500x over previous
//
#include <hip/hip_runtime.h>
#include <hip/hip_fp16.h>

#define BB 8
#define LL 1024
#define DIN 256
#define DM 512
#define HH 8
#define DH 64

typedef __attribute__((ext_vector_type(8))) short bf16x8;
typedef __attribute__((ext_vector_type(4))) float f32x4;

__device__ __forceinline__ unsigned short f2bf(float f) {
  union { float f; unsigned u; } c; c.f = f;
  unsigned u = c.u;
  return (unsigned short)((u + 0x7fffu + ((u >> 16) & 1u)) >> 16);
}

#if defined(__has_builtin)
#if __has_builtin(__builtin_amdgcn_cvt_pk_bf16_f32)
#define HAS_PK_BF16 1
#endif
#endif

#ifdef HAS_PK_BF16
typedef __bf16 bf2 __attribute__((ext_vector_type(2)));
__device__ __forceinline__ unsigned pk2(float lo, float hi) {
  union { bf2 v; unsigned u; } c;
  c.v = __builtin_amdgcn_cvt_pk_bf16_f32(lo, hi);
  return c.u;
}
#else
__device__ __forceinline__ unsigned pk2(float lo, float hi) {
  return ((unsigned)f2bf(hi) << 16) | f2bf(lo);
}
#endif

__device__ __forceinline__ unsigned pkh(float a, float d) {
  return (unsigned)__half_as_ushort(__float2half_rn(a)) |
         ((unsigned)__half_as_ushort(__float2half_rn(d)) << 16);
}

// async global -> LDS DMA, 16 B/lane; LDS dest = wave-uniform base + lane*16
__device__ __forceinline__ void async_copy16(void* lds, const void* g) {
  __builtin_amdgcn_global_load_lds(
      (const __attribute__((address_space(1))) unsigned*)g,
      (__attribute__((address_space(3))) unsigned*)lds, 16, 0, 0);
}

// ---------------- K0: merged precast ----------------
__global__ __launch_bounds__(256) void prep(
    const float* __restrict__ qin, const float* __restrict__ kin,
    const float* __restrict__ vin,
    const float* __restrict__ wq, const float* __restrict__ wk,
    const float* __restrict__ wv, const float* __restrict__ wo,
    const int* __restrict__ msk,
    const float* __restrict__ adj, const float* __restrict__ dis,
    unsigned short* __restrict__ xq, unsigned short* __restrict__ xk,
    unsigned short* __restrict__ xv,
    unsigned short* __restrict__ wqb, unsigned short* __restrict__ wkb,
    unsigned short* __restrict__ wvb, unsigned short* __restrict__ wob,
    float* __restrict__ mad, unsigned* __restrict__ bp)
{
  int t = blockIdx.x * 256 + threadIdx.x;  // quad index
  const int XS = 524288, WS = 32768;
  if (t < 3 * XS) {
    int seg = t >> 19, off = t & (XS - 1);
    const float* s = (seg == 0) ? qin : (seg == 1) ? kin : vin;
    unsigned short* d = (seg == 0) ? xq : (seg == 1) ? xk : xv;
    float4 f = ((const float4*)s)[off];
    uint2 o = { pk2(f.x, f.y), pk2(f.z, f.w) };
    ((uint2*)d)[off] = o;
    return;
  }
  t -= 3 * XS;
  if (t < 3 * WS) {
    int seg = t >> 15, off = t & (WS - 1);
    const float* s = (seg == 0) ? wq : (seg == 1) ? wk : wv;
    unsigned short* d = (seg == 0) ? wqb : (seg == 1) ? wkb : wvb;
    float4 f = ((const float4*)s)[off];
    uint2 o = { pk2(f.x, f.y), pk2(f.z, f.w) };
    ((uint2*)d)[off] = o;
    return;
  }
  t -= 3 * WS;
  if (t < 65536) {
    float4 f = ((const float4*)wo)[t];
    uint2 o = { pk2(f.x, f.y), pk2(f.z, f.w) };
    ((uint2*)wob)[t] = o;
    return;
  }
  t -= 65536;
  if (t < 2048) {
    int4 m = ((const int4*)msk)[t];
    float4 f = { m.x ? 0.0f : -30000.0f, m.y ? 0.0f : -30000.0f,
                 m.z ? 0.0f : -30000.0f, m.w ? 0.0f : -30000.0f };
    ((float4*)mad)[t] = f;
    return;
  }
  t -= 2048;  // bias pack: 2,097,152 quads
  float4 a4 = ((const float4*)adj)[t];
  float4 d4 = ((const float4*)dis)[t];
  uint4 o = { pkh(a4.x, d4.x), pkh(a4.y, d4.y), pkh(a4.z, d4.z), pkh(a4.w, d4.w) };
  ((uint4*)bp)[t] = o;
}

// ---------------- K1: QKV projection, DMA double-buffered ----------------
// grid (8 = head, 64 = mtile, 3 = tensor), block 256 (4 waves).
// One __syncthreads per K-iter: DMA for iter+1 issued before consuming iter.
__global__ __launch_bounds__(256) void qkv_proj(
    const unsigned short* __restrict__ xq, const unsigned short* __restrict__ xk,
    const unsigned short* __restrict__ xv,
    const unsigned short* __restrict__ wqb, const unsigned short* __restrict__ wkb,
    const unsigned short* __restrict__ wvb,
    unsigned short* __restrict__ qb, unsigned short* __restrict__ kb,
    unsigned short* __restrict__ vt)
{
  const int t = blockIdx.z;
  const unsigned short* __restrict__ X = (t == 0) ? xq : (t == 1) ? xk : xv;
  const unsigned short* __restrict__ W = (t == 0) ? wqb : (t == 1) ? wkb : wvb;
  const int m0 = blockIdx.y * 128;
  const int h  = blockIdx.x;
  // arena: A 2x8192 | B 2x4096 = 24576 B
  __shared__ __align__(16) char arena[24576];
  const int tid = threadIdx.x;
  const int wid = tid >> 6;
  const int lane = tid & 63;
  const int lo = lane & 15;
  const int quad = lane >> 4;

  f32x4 acc[2][4];
#pragma unroll
  for (int mi = 0; mi < 2; ++mi)
#pragma unroll
    for (int ni = 0; ni < 4; ++ni) acc[mi][ni] = (f32x4)0.0f;

  // stage iter 0 -> parity 0
#pragma unroll
  for (int j = 0; j < 2; ++j) {
    int id = j * 256 + tid, r = id >> 2, c = id & 3;
    async_copy16(arena + j * 4096 + wid * 1024,
                 X + (size_t)(m0 + r) * DIN + ((c ^ (r & 3)) * 8));
  }
  {
    int id = tid, r = id >> 2, c = id & 3;
    async_copy16(arena + 16384 + wid * 1024,
                 W + (size_t)(h * 64 + r) * DIN + ((c ^ (r & 3)) * 8));
  }
  __syncthreads();

  for (int it = 0; it < 8; ++it) {
    const int p = it & 1;
    if (it < 7) {  // prefetch iter+1 into alt parity
      const int kk = (it + 1) * 32, q = 1 - p;
#pragma unroll
      for (int j = 0; j < 2; ++j) {
        int id = j * 256 + tid, r = id >> 2, c = id & 3;
        async_copy16(arena + q * 8192 + j * 4096 + wid * 1024,
                     X + (size_t)(m0 + r) * DIN + kk + ((c ^ (r & 3)) * 8));
      }
      {
        int id = tid, r = id >> 2, c = id & 3;
        async_copy16(arena + 16384 + q * 4096 + wid * 1024,
                     W + (size_t)(h * 64 + r) * DIN + kk + ((c ^ (r & 3)) * 8));
      }
    }
    const unsigned short* Ab = (const unsigned short*)(arena + p * 8192);
    const unsigned short* Bb = (const unsigned short*)(arena + 16384 + p * 4096);
    bf16x8 a[2], bfr[4];
#pragma unroll
    for (int mi = 0; mi < 2; ++mi) {
      int R = wid * 32 + mi * 16 + lo;
      a[mi] = *(const bf16x8*)&Ab[R * 32 + ((quad ^ (R & 3)) * 8)];
    }
#pragma unroll
    for (int ni = 0; ni < 4; ++ni) {
      int N = ni * 16 + lo;
      bfr[ni] = *(const bf16x8*)&Bb[N * 32 + ((quad ^ (N & 3)) * 8)];
    }
#pragma unroll
    for (int mi = 0; mi < 2; ++mi)
#pragma unroll
      for (int ni = 0; ni < 4; ++ni)
        acc[mi][ni] = __builtin_amdgcn_mfma_f32_16x16x32_bf16(
            a[mi], bfr[ni], acc[mi][ni], 0, 0, 0);
    __syncthreads();
  }

  const int b = m0 >> 10;
  const int lbase0 = (m0 & 1023) + wid * 32;
  if (t < 2) {
    unsigned short* dstp = (t == 0) ? qb : kb;
#pragma unroll
    for (int mi = 0; mi < 2; ++mi)
#pragma unroll
      for (int ni = 0; ni < 4; ++ni) {
        int d = ni * 16 + lo;
#pragma unroll
        for (int r = 0; r < 4; ++r) {
          int lb = lbase0 + mi * 16 + quad * 4 + r;
          dstp[((size_t)(b * HH + h) * LL + lb) * DH + d] = f2bf(acc[mi][ni][r]);
        }
      }
  } else {
#pragma unroll
    for (int mi = 0; mi < 2; ++mi)
#pragma unroll
      for (int ni = 0; ni < 4; ++ni) {
        int d = ni * 16 + lo;
        int lb = lbase0 + mi * 16 + quad * 4;
        uint2 o = { pk2(acc[mi][ni][0], acc[mi][ni][1]),
                    pk2(acc[mi][ni][2], acc[mi][ni][3]) };
        *(uint2*)&vt[((size_t)(b * HH + h) * DH + d) * LL + lb] = o;
      }
  }
}

// ---------------- K2: fused biased attention, DMA double-buffered ----------
// grid 1024: idx = qt*32 + hg*8 + b (XCD swizzle). 4 waves/block:
// (h = hg*2 + wid&1, K-half = wid>>1). One __syncthreads per tile:
// DMA for tile+1 issued into alt parity before consuming current tile.
__global__ __launch_bounds__(256) void attn(
    const unsigned short* __restrict__ qb, const unsigned short* __restrict__ kb,
    const unsigned short* __restrict__ vt,
    const float* __restrict__ mad, const unsigned* __restrict__ bp,
    const float* __restrict__ la_, const float* __restrict__ ld_,
    unsigned short* __restrict__ ao)
{
  const int bi = blockIdx.x;
  const int b  = bi & 7;
  const int hg = (bi >> 3) & 3;
  const int q0 = (bi >> 5) * 32;
  const int tid = threadIdx.x;
  const int wid = tid >> 6;
  const int lane = tid & 63;
  const int lo = lane & 15;
  const int quad = lane >> 4;
  const int h  = hg * 2 + (wid & 1);
  const int kh = wid >> 1;
  const int bh = b * HH + h;

  // arena: kbuf 2x16384 | bbuf 2x8192 | pbuf 4x2560 = 59392 B
  __shared__ __align__(16) char arena[59392];
  unsigned short* pbufw = (unsigned short*)(arena + 49152) + wid * 1280;
  float*          mgbuf = (float*)arena;  // merge alias (post-loop)

  const float LOG2E = 1.44269504f;
  const float la2 = la_[h] * LOG2E, ld2 = ld_[h] * LOG2E;
  const float sc2 = 0.125f * LOG2E;

  const unsigned short* qp = qb + ((size_t)bh * LL + q0) * DH;
  bf16x8 qB[2][2];
#pragma unroll
  for (int nj = 0; nj < 2; ++nj)
#pragma unroll
    for (int ki = 0; ki < 2; ++ki)
      qB[nj][ki] = *(const bf16x8*)&qp[(nj * 16 + lo) * DH + ki * 32 + quad * 8];

  const unsigned short* kp = kb + (size_t)bh * LL * DH;
  const unsigned short* vp = vt + (size_t)bh * DH * LL;
  const unsigned* bpp = bp + ((size_t)b * LL + q0) * LL;
  const float* mp = mad + b * LL;

  f32x4 o[4][2];
  float rs[2] = {0.0f, 0.0f};
#pragma unroll
  for (int md = 0; md < 4; ++md)
#pragma unroll
    for (int nj = 0; nj < 2; ++nj) o[md][nj] = (f32x4)0.0f;

  const int kbeg = kh * (LL / 2);
  const int r8 = lane >> 3, p8 = lane & 7;

  // stage tile 0 -> parity 0
  {
    const unsigned short* kg = kp + (size_t)kbeg * DH;
#pragma unroll
    for (int j = 0; j < 4; ++j)
      async_copy16(arena + wid * 4096 + j * 1024,
                   kg + (j * 8 + r8) * 64 + ((p8 ^ r8) * 8));
    if ((wid & 1) == 0) {
      const int khs = wid >> 1;
      const unsigned* bg = bpp + khs * (LL / 2);
#pragma unroll
      for (int j = 0; j < 4; ++j)
        async_copy16(arena + 32768 + khs * 4096 + j * 1024,
                     bg + (size_t)(j * 8 + r8) * LL + ((p8 ^ r8) * 4));
    }
  }
  __syncthreads();

  for (int jt = 0; jt < 16; ++jt) {
    const int p = jt & 1;
    const int k0 = kbeg + jt * 32;

    if (jt < 15) {  // prefetch tile+1 into alt parity
      const int kn = k0 + 32, q = 1 - p;
      const unsigned short* kg = kp + (size_t)kn * DH;
#pragma unroll
      for (int j = 0; j < 4; ++j)
        async_copy16(arena + q * 16384 + wid * 4096 + j * 1024,
                     kg + (j * 8 + r8) * 64 + ((p8 ^ r8) * 8));
      if ((wid & 1) == 0) {
        const int khs = wid >> 1;
        const unsigned* bg = bpp + khs * (LL / 2) + (jt + 1) * 32;
#pragma unroll
        for (int j = 0; j < 4; ++j)
          async_copy16(arena + 32768 + q * 8192 + khs * 4096 + j * 1024,
                       bg + (size_t)(j * 8 + r8) * LL + ((p8 ^ r8) * 4));
      }
    }

    // V + mask direct to VGPR (consumed at tile end / mid)
    bf16x8 vA[4];
#pragma unroll
    for (int md = 0; md < 4; ++md)
      vA[md] = *(const bf16x8*)&vp[(md * 16 + lo) * LL + k0 + quad * 8];
    f32x4 msv[2];
#pragma unroll
    for (int mi = 0; mi < 2; ++mi)
      msv[mi] = *(const f32x4*)&mp[k0 + mi * 16 + quad * 4];

    // ---- consume parity p ----
    const unsigned short* kbf = (const unsigned short*)(arena + p * 16384) + wid * 2048;
    const unsigned* bbf = (const unsigned*)(arena + 32768 + p * 8192) + kh * 1024;

    bf16x8 kA[2][2];
#pragma unroll
    for (int mi = 0; mi < 2; ++mi)
#pragma unroll
      for (int ki = 0; ki < 2; ++ki)
        kA[mi][ki] = *(const bf16x8*)&kbf[(mi * 16 + lo) * 64 +
                                          (((ki * 4 + quad) ^ (lo & 7)) * 8)];
    f32x4 s[2][2];
#pragma unroll
    for (int mi = 0; mi < 2; ++mi)
#pragma unroll
      for (int nj = 0; nj < 2; ++nj) s[mi][nj] = (f32x4)0.0f;
#pragma unroll
    for (int ki = 0; ki < 2; ++ki)
#pragma unroll
      for (int mi = 0; mi < 2; ++mi)
#pragma unroll
        for (int nj = 0; nj < 2; ++nj)
          s[mi][nj] = __builtin_amdgcn_mfma_f32_16x16x32_bf16(
              kA[mi][ki], qB[nj][ki], s[mi][nj], 0, 0, 0);

#pragma unroll
    for (int mi = 0; mi < 2; ++mi)
#pragma unroll
      for (int nj = 0; nj < 2; ++nj) {
        uint4 u = *(const uint4*)&bbf[(nj * 16 + lo) * 32 +
                                      (((mi * 4 + quad) ^ (lo & 7)) * 4)];
        float p4[4];
#pragma unroll
        for (int r = 0; r < 4; ++r) {
          union { unsigned v; __half2 hh; } c; c.v = u[r];
          float tt = fmaf(__high2float(c.hh), ld2, msv[mi][r]);
          tt = fmaf(__low2float(c.hh), la2, tt);
          p4[r] = __builtin_amdgcn_exp2f(fmaf(s[mi][nj][r], sc2, tt));
        }
        rs[nj] += (p4[0] + p4[1]) + (p4[2] + p4[3]);
        uint2 w = { pk2(p4[0], p4[1]), pk2(p4[2], p4[3]) };
        *(uint2*)&pbufw[(nj * 16 + lo) * 40 + mi * 16 + quad * 4] = w;
      }

    asm volatile("s_waitcnt lgkmcnt(0)" ::: "memory");

    bf16x8 pB[2];
#pragma unroll
    for (int nj = 0; nj < 2; ++nj)
      pB[nj] = *(const bf16x8*)&pbufw[(nj * 16 + lo) * 40 + quad * 8];

#pragma unroll
    for (int md = 0; md < 4; ++md)
#pragma unroll
      for (int nj = 0; nj < 2; ++nj)
        o[md][nj] = __builtin_amdgcn_mfma_f32_16x16x32_bf16(
            vA[md], pB[nj], o[md][nj], 0, 0, 0);

    __syncthreads();  // drains own DMA (tile+1) + protects parity flip
  }

  // merge the two K-halves (mgbuf aliases stage buffers, dead now)
  const int hs = wid & 1;
  if (kh == 1) {
#pragma unroll
    for (int md = 0; md < 4; ++md)
#pragma unroll
      for (int nj = 0; nj < 2; ++nj)
#pragma unroll
        for (int r = 0; r < 4; ++r)
          mgbuf[hs * 2176 + ((md * 2 + nj) * 4 + r) * 64 + lane] = o[md][nj][r];
    mgbuf[hs * 2176 + 32 * 64 + lane] = rs[0];
    mgbuf[hs * 2176 + 33 * 64 + lane] = rs[1];
  }
  __syncthreads();
  if (kh == 0) {
#pragma unroll
    for (int md = 0; md < 4; ++md)
#pragma unroll
      for (int nj = 0; nj < 2; ++nj)
#pragma unroll
        for (int r = 0; r < 4; ++r)
          o[md][nj][r] += mgbuf[hs * 2176 + ((md * 2 + nj) * 4 + r) * 64 + lane];
    rs[0] += mgbuf[hs * 2176 + 32 * 64 + lane];
    rs[1] += mgbuf[hs * 2176 + 33 * 64 + lane];
    float inv[2];
#pragma unroll
    for (int nj = 0; nj < 2; ++nj) {
      rs[nj] += __shfl_xor(rs[nj], 16);
      rs[nj] += __shfl_xor(rs[nj], 32);
      inv[nj] = __builtin_amdgcn_rcpf(rs[nj]);
    }
#pragma unroll
    for (int md = 0; md < 4; ++md)
#pragma unroll
      for (int nj = 0; nj < 2; ++nj) {
        int l = q0 + nj * 16 + lo;
        uint2 st = { pk2(o[md][nj][0] * inv[nj], o[md][nj][1] * inv[nj]),
                     pk2(o[md][nj][2] * inv[nj], o[md][nj][3] * inv[nj]) };
        *(uint2*)&ao[((size_t)b * LL + l) * DM + h * DH + md * 16 + quad * 4] = st;
      }
  }
}

// ---------------- K3: output projection, DMA double-buffered ----------------
// grid (8 ntile, 64 mtile), block 256
__global__ __launch_bounds__(256) void oproj(
    const unsigned short* __restrict__ ao, const unsigned short* __restrict__ wob,
    float* __restrict__ out)
{
  const int m0 = blockIdx.y * 128;
  const int n0 = blockIdx.x * 64;
  __shared__ __align__(16) char arena[24576];
  const int tid = threadIdx.x;
  const int wid = tid >> 6;
  const int lane = tid & 63;
  const int lo = lane & 15;
  const int quad = lane >> 4;

  f32x4 acc[2][4];
#pragma unroll
  for (int mi = 0; mi < 2; ++mi)
#pragma unroll
    for (int ni = 0; ni < 4; ++ni) acc[mi][ni] = (f32x4)0.0f;

  // stage iter 0 -> parity 0
#pragma unroll
  for (int j = 0; j < 2; ++j) {
    int id = j * 256 + tid, r = id >> 2, c = id & 3;
    async_copy16(arena + j * 4096 + wid * 1024,
                 ao + (size_t)(m0 + r) * DM + ((c ^ (r & 3)) * 8));
  }
  {
    int id = tid, r = id >> 2, c = id & 3;
    async_copy16(arena + 16384 + wid * 1024,
                 wob + (size_t)(n0 + r) * DM + ((c ^ (r & 3)) * 8));
  }
  __syncthreads();

  for (int it = 0; it < 16; ++it) {
    const int p = it & 1;
    if (it < 15) {
      const int kk = (it + 1) * 32, q = 1 - p;
#pragma unroll
      for (int j = 0; j < 2; ++j) {
        int id = j * 256 + tid, r = id >> 2, c = id & 3;
        async_copy16(arena + q * 8192 + j * 4096 + wid * 1024,
                     ao + (size_t)(m0 + r) * DM + kk + ((c ^ (r & 3)) * 8));
      }
      {
        int id = tid, r = id >> 2, c = id & 3;
        async_copy16(arena + 16384 + q * 4096 + wid * 1024,
                     wob + (size_t)(n0 + r) * DM + kk + ((c ^ (r & 3)) * 8));
      }
    }
    const unsigned short* Ab = (const unsigned short*)(arena + p * 8192);
    const unsigned short* Bb = (const unsigned short*)(arena + 16384 + p * 4096);
    bf16x8 a[2], bfr[4];
#pragma unroll
    for (int mi = 0; mi < 2; ++mi) {
      int R = wid * 32 + mi * 16 + lo;
      a[mi] = *(const bf16x8*)&Ab[R * 32 + ((quad ^ (R & 3)) * 8)];
    }
#pragma unroll
    for (int ni = 0; ni < 4; ++ni) {
      int N = ni * 16 + lo;
      bfr[ni] = *(const bf16x8*)&Bb[N * 32 + ((quad ^ (N & 3)) * 8)];
    }
#pragma unroll
    for (int mi = 0; mi < 2; ++mi)
#pragma unroll
      for (int ni = 0; ni < 4; ++ni)
        acc[mi][ni] = __builtin_amdgcn_mfma_f32_16x16x32_bf16(
            a[mi], bfr[ni], acc[mi][ni], 0, 0, 0);
    __syncthreads();
  }

#pragma unroll
  for (int mi = 0; mi < 2; ++mi)
#pragma unroll
    for (int ni = 0; ni < 4; ++ni)
#pragma unroll
      for (int r = 0; r < 4; ++r)
        out[(size_t)(m0 + wid * 32 + mi * 16 + quad * 4 + r) * DM +
            n0 + ni * 16 + lo] = acc[mi][ni][r];
}

extern "C" void kernel_launch(void* const* d_in, const int* in_sizes, int n_in,
                              void* d_out, int out_size, void* d_ws, size_t ws_size,
                              hipStream_t stream) {
  const float* qin = (const float*)d_in[0];
  const float* kin = (const float*)d_in[1];
  const float* vin = (const float*)d_in[2];
  const int*   msk = (const int*)d_in[3];
  const float* adj = (const float*)d_in[4];
  const float* dis = (const float*)d_in[5];
  const float* wq  = (const float*)d_in[6];
  const float* wk  = (const float*)d_in[7];
  const float* wv  = (const float*)d_in[8];
  const float* wo  = (const float*)d_in[9];
  const float* la  = (const float*)d_in[10];
  const float* ld  = (const float*)d_in[11];
  float* out = (float*)d_out;

  const size_t tensb = (size_t)BB * HH * LL * DH;   // 4,194,304
  const size_t xsz   = (size_t)BB * LL * DIN;       // 2,097,152
  unsigned short* qb  = (unsigned short*)d_ws;
  unsigned short* kb  = qb + tensb;
  unsigned short* vt  = kb + tensb;
  unsigned short* ao  = vt + tensb;                 // (B,L,512) bf16
  unsigned short* xq  = ao;                         // alias (dead until attn)
  unsigned short* xk  = ao + xsz;
  unsigned short* xv  = ao + tensb;
  unsigned short* wqb = xv + xsz;
  unsigned short* wkb = wqb + (size_t)DM * DIN;
  unsigned short* wvb = wkb + (size_t)DM * DIN;
  unsigned short* wob = wvb + (size_t)DM * DIN;
  float*          mdd = (float*)(wob + (size_t)DM * DM);
  unsigned*       bpk = (unsigned*)(mdd + (size_t)BB * LL);  // 33.5 MB packed bias

  prep<<<dim3(14984), 256, 0, stream>>>(qin, kin, vin, wq, wk, wv, wo, msk,
                                        adj, dis,
                                        xq, xk, xv, wqb, wkb, wvb, wob, mdd, bpk);
  qkv_proj<<<dim3(8, 64, 3), 256, 0, stream>>>(xq, xk, xv, wqb, wkb, wvb, qb, kb, vt);
  attn<<<dim3(1024), 256, 0, stream>>>(qb, kb, vt, mdd, bpk, la, ld, ao);
  oproj<<<dim3(8, 64), 256, 0, stream>>>(ao, wob, out);
}